// Round 1
// baseline (309.164 us; speedup 1.0000x reference)
//
#include <hip/hip_runtime.h>
#include <hip/hip_bf16.h>

// B=4, N=8192, E=1024, D=64 ; ROWS = B*N = 32768
// out = ((x@wq^T) @ (K^T V) * sqrt(3/64)) @ wo^T,  K = x@wk^T, V = x@wv^T
//
// Precision strategy: weights are exactly representable in bf16 (+-2^-5, +-2^-3),
// activations are split x = hi + lo (both bf16) -> two MFMA passes accumulate in
// fp32. Residual error ~3e-5 relative: near-fp32 accuracy at MFMA rates.

typedef __bf16 bf16x8 __attribute__((ext_vector_type(8)));
typedef float  f32x4  __attribute__((ext_vector_type(4)));

#define MFMA_BF16(A, Bb, C) __builtin_amdgcn_mfma_f32_16x16x32_bf16(A, Bb, C, 0, 0, 0)

__device__ inline __bf16 bf16_trunc(float v) {
    // exact for weights (low mantissa bits are zero)
    return __builtin_bit_cast(__bf16, (unsigned short)(__float_as_uint(v) >> 16));
}

// ---------------------------------------------------------------------------
// K1: QKV projection GEMM.  C[32768 x 192] = split(x)[32768 x 1024] @ W^T
// tile: 128 rows x 192 cols, BK=64, 8 waves (4m x 2n), 16x16x32 bf16 MFMA.
// LDS tiles XOR-swizzled by (row&7)/(col&7) to kill stride-128B bank conflicts.
// ---------------------------------------------------------------------------
__global__ __launch_bounds__(512) void qkv_kernel(
    const float* __restrict__ x,  const float* __restrict__ wq,
    const float* __restrict__ wk, const float* __restrict__ wv,
    float* __restrict__ Qf, float* __restrict__ Kf, float* __restrict__ Vf)
{
    __shared__ __bf16 xh[128 * 64];
    __shared__ __bf16 xl[128 * 64];
    __shared__ __bf16 wl[192 * 64];

    const int tid  = threadIdx.x;
    const int lane = tid & 63;
    const int wid  = tid >> 6;
    const int lr   = lane & 15;
    const int kg   = lane >> 4;
    const int wm   = wid >> 1;          // 0..3 : 32-row group
    const int wn   = wid & 1;           // 0..1 : 96-col group
    const int row0 = blockIdx.x * 128;

    const int sr = tid >> 2;            // staging row (0..127)
    const int sk = (tid & 3) * 16;      // staging k offset

    f32x4 acc[2][6];
#pragma unroll
    for (int i = 0; i < 2; ++i)
#pragma unroll
        for (int j = 0; j < 6; ++j) acc[i][j] = (f32x4){0.f, 0.f, 0.f, 0.f};

    for (int step = 0; step < 16; ++step) {
        // ---- stage x tile: fp32 -> (hi,lo) bf16, swizzled ----
        {
            const float* src = x + (size_t)(row0 + sr) * 1024 + step * 64 + sk;
            float v[16];
            *(float4*)&v[0]  = *(const float4*)(src + 0);
            *(float4*)&v[4]  = *(const float4*)(src + 4);
            *(float4*)&v[8]  = *(const float4*)(src + 8);
            *(float4*)&v[12] = *(const float4*)(src + 12);
            bf16x8 h0, h1, l0, l1;
#pragma unroll
            for (int i = 0; i < 8; ++i) {
                unsigned int b0 = __float_as_uint(v[i]);
                h0[i] = __builtin_bit_cast(__bf16, (unsigned short)(b0 >> 16));
                l0[i] = (__bf16)(v[i] - __uint_as_float(b0 & 0xffff0000u));
                unsigned int b1 = __float_as_uint(v[8 + i]);
                h1[i] = __builtin_bit_cast(__bf16, (unsigned short)(b1 >> 16));
                l1[i] = (__bf16)(v[8 + i] - __uint_as_float(b1 & 0xffff0000u));
            }
            const int s0 = sk >> 3;                      // 0,2,4,6
            const int p0 = ((s0    ) ^ (sr & 7)) << 3;
            const int p1 = ((s0 + 1) ^ (sr & 7)) << 3;
            *(bf16x8*)&xh[sr * 64 + p0] = h0;
            *(bf16x8*)&xh[sr * 64 + p1] = h1;
            *(bf16x8*)&xl[sr * 64 + p0] = l0;
            *(bf16x8*)&xl[sr * 64 + p1] = l1;
        }
        // ---- stage W tile (exact bf16), swizzled; 1536 slots of 8 ----
#pragma unroll
        for (int i = 0; i < 3; ++i) {
            const int sid = tid + i * 512;               // 0..1535
            const int col = sid >> 3;
            const int sig = sid & 7;
            const int kk  = step * 64 + ((sig ^ (col & 7)) << 3);
            const float* wsrc = (col < 64)  ? (wq + (size_t)col * 1024 + kk)
                              : (col < 128) ? (wk + (size_t)(col - 64) * 1024 + kk)
                                            : (wv + (size_t)(col - 128) * 1024 + kk);
            float w[8];
            *(float4*)&w[0] = *(const float4*)(wsrc + 0);
            *(float4*)&w[4] = *(const float4*)(wsrc + 4);
            bf16x8 wb;
#pragma unroll
            for (int j = 0; j < 8; ++j) wb[j] = bf16_trunc(w[j]);
            *(bf16x8*)&wl[col * 64 + sig * 8] = wb;
        }
        __syncthreads();
        // ---- MFMA: 2 k-slices of 32, hi+lo into same accumulators ----
#pragma unroll
        for (int ks = 0; ks < 2; ++ks) {
            bf16x8 Ah[2], Al[2], Bw[6];
#pragma unroll
            for (int am = 0; am < 2; ++am) {
                const int row  = wm * 32 + am * 16 + lr;
                const int slot = ks * 4 + kg;
                const int off  = row * 64 + ((slot ^ (row & 7)) << 3);
                Ah[am] = *(const bf16x8*)&xh[off];
                Al[am] = *(const bf16x8*)&xl[off];
            }
#pragma unroll
            for (int bn = 0; bn < 6; ++bn) {
                const int col  = wn * 96 + bn * 16 + lr;
                const int slot = ks * 4 + kg;
                Bw[bn] = *(const bf16x8*)&wl[col * 64 + ((slot ^ (col & 7)) << 3)];
            }
#pragma unroll
            for (int am = 0; am < 2; ++am)
#pragma unroll
                for (int bn = 0; bn < 6; ++bn) {
                    acc[am][bn] = MFMA_BF16(Ah[am], Bw[bn], acc[am][bn]);
                    acc[am][bn] = MFMA_BF16(Al[am], Bw[bn], acc[am][bn]);
                }
        }
        __syncthreads();
    }
    // ---- epilogue: C/D layout col=lane&15, row=(lane>>4)*4+reg ----
#pragma unroll
    for (int am = 0; am < 2; ++am)
#pragma unroll
        for (int bn = 0; bn < 6; ++bn) {
            const int col = wn * 96 + bn * 16 + lr;
            float* dst = (col < 64) ? Qf : (col < 128) ? Kf : Vf;
            const int cc = col & 63;
            const int rb = row0 + wm * 32 + am * 16 + kg * 4;
#pragma unroll
            for (int r = 0; r < 4; ++r)
                dst[(size_t)(rb + r) * 64 + cc] = acc[am][bn][r];
        }
}

// ---------------------------------------------------------------------------
// K2: partial energy.  part[blk][d][e] = sum over the block's 128 rows K[n,d]V[n,e]
// ---------------------------------------------------------------------------
__global__ __launch_bounds__(256) void energy_partial_kernel(
    const float* __restrict__ Kf, const float* __restrict__ Vf,
    float* __restrict__ part)
{
    __shared__ float lK[32][64];
    __shared__ float lV[32][64];
    const int tid  = threadIdx.x;
    const int d    = tid >> 2;
    const int e0   = (tid & 3) << 4;
    const int row0 = blockIdx.x * 128;

    float acc[16];
#pragma unroll
    for (int j = 0; j < 16; ++j) acc[j] = 0.f;

    for (int base = 0; base < 128; base += 32) {
        __syncthreads();
#pragma unroll
        for (int i = 0; i < 2; ++i) {
            const int idx = tid + i * 256;               // float4 index 0..511
            const int r   = idx >> 4;
            const int c4  = (idx & 15) << 2;
            *(float4*)&lK[r][c4] = *(const float4*)&Kf[(size_t)(row0 + base + r) * 64 + c4];
            *(float4*)&lV[r][c4] = *(const float4*)&Vf[(size_t)(row0 + base + r) * 64 + c4];
        }
        __syncthreads();
        for (int n = 0; n < 32; ++n) {
            const float kv = lK[n][d];
            const float4 a = *(const float4*)&lV[n][e0];
            const float4 b = *(const float4*)&lV[n][e0 + 4];
            const float4 c = *(const float4*)&lV[n][e0 + 8];
            const float4 e = *(const float4*)&lV[n][e0 + 12];
            acc[0]  += kv * a.x; acc[1]  += kv * a.y; acc[2]  += kv * a.z; acc[3]  += kv * a.w;
            acc[4]  += kv * b.x; acc[5]  += kv * b.y; acc[6]  += kv * b.z; acc[7]  += kv * b.w;
            acc[8]  += kv * c.x; acc[9]  += kv * c.y; acc[10] += kv * c.z; acc[11] += kv * c.w;
            acc[12] += kv * e.x; acc[13] += kv * e.y; acc[14] += kv * e.z; acc[15] += kv * e.w;
        }
    }
    float* p = part + (size_t)blockIdx.x * 4096 + d * 64 + e0;
#pragma unroll
    for (int i = 0; i < 4; ++i)
        *(float4*)&p[i * 4] = make_float4(acc[i*4+0], acc[i*4+1], acc[i*4+2], acc[i*4+3]);
}

// K2b: energy[b][..] = sum over the batch's 64 chunk partials
__global__ __launch_bounds__(256) void energy_reduce_kernel(
    const float* __restrict__ part, float* __restrict__ energy)
{
    const int b    = blockIdx.x >> 4;
    const int elem = ((blockIdx.x & 15) << 8) + threadIdx.x;
    float s = 0.f;
#pragma unroll 8
    for (int c = 0; c < 64; ++c)
        s += part[(size_t)(b * 64 + c) * 4096 + elem];
    energy[b * 4096 + elem] = s;
}

// ---------------------------------------------------------------------------
// K3: out = (Q @ (energy*scale)) @ wo^T.  128 rows/block; context in fp32 VALU,
// split to bf16 hi/lo in LDS; then MFMA over 4 column tiles of 256.
// ---------------------------------------------------------------------------
__global__ __launch_bounds__(512) void out_kernel(
    const float* __restrict__ Qf, const float* __restrict__ energy,
    const float* __restrict__ wo, float* __restrict__ out)
{
    __shared__ __align__(16) unsigned char lds[83968];
    __bf16* ctxh = (__bf16*)lds;                        // [128][64] bf16, swizzled
    __bf16* ctxl = (__bf16*)(lds + 16384);
    float*  Qs   = (float*)(lds + 32768);               // [128][68] fp32 (padded)
    float*  Es   = (float*)(lds + 32768 + 34816);       // [64][64] fp32 (pre-scaled)
    __bf16* wls  = (__bf16*)(lds + 32768);              // [256][64] bf16 (aliases Qs/Es)

    const int tid  = threadIdx.x;
    const int lane = tid & 63;
    const int wid  = tid >> 6;
    const int lr   = lane & 15;
    const int kg   = lane >> 4;
    const int row0 = blockIdx.x * 128;
    const int b    = blockIdx.x >> 6;                   // 64 blocks per batch
    const float scale = 0.2165063509461097f;            // sqrt(3/64)

    // ---- load Q chunk (padded) and scaled energy ----
    {
        const int r  = tid >> 2;
        const int k0 = (tid & 3) << 4;
        const float* src = Qf + (size_t)(row0 + r) * 64 + k0;
#pragma unroll
        for (int i = 0; i < 4; ++i)
            *(float4*)&Qs[r * 68 + k0 + i * 4] = *(const float4*)(src + i * 4);
#pragma unroll
        for (int i = 0; i < 2; ++i) {
            const int idx = (tid + i * 512) << 2;       // 0..4092
            float4 ev = *(const float4*)&energy[b * 4096 + idx];
            ev.x *= scale; ev.y *= scale; ev.z *= scale; ev.w *= scale;
            *(float4*)&Es[idx] = ev;
        }
    }
    __syncthreads();
    // ---- context = Q @ E (fp32), split to bf16 hi/lo ----
    {
        const int row = tid >> 2;
        const int e0  = (tid & 3) << 4;
        float a[16];
#pragma unroll
        for (int j = 0; j < 16; ++j) a[j] = 0.f;
        for (int dd = 0; dd < 64; ++dd) {
            const float q = Qs[row * 68 + dd];
            const float4 v0 = *(const float4*)&Es[dd * 64 + e0];
            const float4 v1 = *(const float4*)&Es[dd * 64 + e0 + 4];
            const float4 v2 = *(const float4*)&Es[dd * 64 + e0 + 8];
            const float4 v3 = *(const float4*)&Es[dd * 64 + e0 + 12];
            a[0]  += q * v0.x; a[1]  += q * v0.y; a[2]  += q * v0.z; a[3]  += q * v0.w;
            a[4]  += q * v1.x; a[5]  += q * v1.y; a[6]  += q * v1.z; a[7]  += q * v1.w;
            a[8]  += q * v2.x; a[9]  += q * v2.y; a[10] += q * v2.z; a[11] += q * v2.w;
            a[12] += q * v3.x; a[13] += q * v3.y; a[14] += q * v3.z; a[15] += q * v3.w;
        }
        bf16x8 h[2], l[2];
#pragma unroll
        for (int g = 0; g < 2; ++g)
#pragma unroll
            for (int j = 0; j < 8; ++j) {
                const float vv = a[g * 8 + j];
                const unsigned int bb = __float_as_uint(vv);
                h[g][j] = __builtin_bit_cast(__bf16, (unsigned short)(bb >> 16));
                l[g][j] = (__bf16)(vv - __uint_as_float(bb & 0xffff0000u));
            }
        const int s0 = e0 >> 3;
        const int p0 = ((s0    ) ^ (row & 7)) << 3;
        const int p1 = ((s0 + 1) ^ (row & 7)) << 3;
        *(bf16x8*)&ctxh[row * 64 + p0] = h[0];
        *(bf16x8*)&ctxh[row * 64 + p1] = h[1];
        *(bf16x8*)&ctxl[row * 64 + p0] = l[0];
        *(bf16x8*)&ctxl[row * 64 + p1] = l[1];
    }
    __syncthreads();

    // ---- out GEMM: waves 2m x 4n over 128 x 256 tiles ----
    const int wm = wid >> 2;
    const int wn = wid & 3;
    for (int nt = 0; nt < 4; ++nt) {
        if (nt) __syncthreads();
        // stage wo tile [256][64] bf16 (exact), swizzled; 2048 slots
#pragma unroll
        for (int i = 0; i < 4; ++i) {
            const int sid = tid + i * 512;
            const int col = sid >> 3;
            const int sig = sid & 7;
            const float* src = wo + (size_t)(nt * 256 + col) * 64 + ((sig ^ (col & 7)) << 3);
            float w[8];
            *(float4*)&w[0] = *(const float4*)(src + 0);
            *(float4*)&w[4] = *(const float4*)(src + 4);
            bf16x8 wb;
#pragma unroll
            for (int j = 0; j < 8; ++j) wb[j] = bf16_trunc(w[j]);
            *(bf16x8*)&wls[col * 64 + sig * 8] = wb;
        }
        __syncthreads();

        f32x4 acc[4][4];
#pragma unroll
        for (int i = 0; i < 4; ++i)
#pragma unroll
            for (int j = 0; j < 4; ++j) acc[i][j] = (f32x4){0.f, 0.f, 0.f, 0.f};

#pragma unroll
        for (int ks = 0; ks < 2; ++ks) {
            bf16x8 Ah[4], Al[4], Bw[4];
#pragma unroll
            for (int am = 0; am < 4; ++am) {
                const int row  = wm * 64 + am * 16 + lr;
                const int slot = ks * 4 + kg;
                const int off  = row * 64 + ((slot ^ (row & 7)) << 3);
                Ah[am] = *(const bf16x8*)&ctxh[off];
                Al[am] = *(const bf16x8*)&ctxl[off];
            }
#pragma unroll
            for (int bn = 0; bn < 4; ++bn) {
                const int col  = wn * 64 + bn * 16 + lr;
                const int slot = ks * 4 + kg;
                Bw[bn] = *(const bf16x8*)&wls[col * 64 + ((slot ^ (col & 7)) << 3)];
            }
#pragma unroll
            for (int am = 0; am < 4; ++am)
#pragma unroll
                for (int bn = 0; bn < 4; ++bn) {
                    acc[am][bn] = MFMA_BF16(Ah[am], Bw[bn], acc[am][bn]);
                    acc[am][bn] = MFMA_BF16(Al[am], Bw[bn], acc[am][bn]);
                }
        }
        // store
#pragma unroll
        for (int am = 0; am < 4; ++am)
#pragma unroll
            for (int bn = 0; bn < 4; ++bn) {
                const int gcol = nt * 256 + wn * 64 + bn * 16 + lr;
                const int grow = row0 + wm * 64 + am * 16 + kg * 4;
#pragma unroll
                for (int r = 0; r < 4; ++r)
                    out[(size_t)(grow + r) * 1024 + gcol] = acc[am][bn][r];
            }
    }
}

extern "C" void kernel_launch(void* const* d_in, const int* in_sizes, int n_in,
                              void* d_out, int out_size, void* d_ws, size_t ws_size,
                              hipStream_t stream)
{
    const float* x  = (const float*)d_in[0];
    const float* wq = (const float*)d_in[1];
    const float* wk = (const float*)d_in[2];
    const float* wv = (const float*)d_in[3];
    const float* wo = (const float*)d_in[4];
    float* out = (float*)d_out;

    char* ws = (char*)d_ws;
    float* Qf     = (float*)(ws);                       //  8,388,608 B
    float* Kf     = (float*)(ws + 8388608);             //  8,388,608 B
    float* Vf     = (float*)(ws + 16777216);            //  8,388,608 B
    float* part   = (float*)(ws + 25165824);            //  4,194,304 B
    float* energy = (float*)(ws + 29360128);            //     65,536 B

    qkv_kernel<<<256, 512, 0, stream>>>(x, wq, wk, wv, Qf, Kf, Vf);
    energy_partial_kernel<<<256, 256, 0, stream>>>(Kf, Vf, part);
    energy_reduce_kernel<<<64, 256, 0, stream>>>(part, energy);
    out_kernel<<<256, 512, 0, stream>>>(Qf, energy, wo, out);
}

// Round 2
// 293.532 us; speedup vs baseline: 1.0533x; 1.0533x over previous
//
#include <hip/hip_runtime.h>
#include <hip/hip_bf16.h>
#include <stdint.h>

// B=4, N=8192, E=1024, D=64 ; ROWS = 32768
// out = ((x@wq^T) @ (K^T V) * sqrt(3/64)) @ wo^T
// Precision: weights exact in bf16; activations split hi/lo bf16 -> fp32 MFMA acc.

typedef __bf16 bf16x8 __attribute__((ext_vector_type(8)));
typedef __bf16 bf16x4 __attribute__((ext_vector_type(4)));
typedef float  f32x4  __attribute__((ext_vector_type(4)));

#define MFMA_BF16(A, Bb, C) __builtin_amdgcn_mfma_f32_16x16x32_bf16(A, Bb, C, 0, 0, 0)

__device__ __forceinline__ int swz8(int row, int slot) { return (slot ^ (row & 7)) << 3; }

__device__ __forceinline__ void gload_lds16(const void* g, void* l) {
    __builtin_amdgcn_global_load_lds(
        (const __attribute__((address_space(1))) unsigned int*)g,
        (__attribute__((address_space(3))) unsigned int*)l, 16, 0, 0);
}

// ---------------------------------------------------------------------------
// P0: weights -> bf16.  Wt: per-step pre-swizzled [16][192][64] tiles for
// direct global_load_lds staging in K1.  Wob: [1024][64] plain row-major.
// ---------------------------------------------------------------------------
__global__ __launch_bounds__(256) void prep_kernel(
    const float* __restrict__ wq, const float* __restrict__ wk,
    const float* __restrict__ wv, const float* __restrict__ wo,
    __bf16* __restrict__ Wt, __bf16* __restrict__ Wob)
{
    const int idx = blockIdx.x * 256 + threadIdx.x;      // 0..32767
    if (idx < 24576) {                                   // Wt chunks
        const int col  = idx >> 7;                       // 0..191
        const int rem  = idx & 127;
        const int step = rem >> 3;
        const int slot = rem & 7;
        const float* src = (col < 64)  ? wq + (size_t)col * 1024
                         : (col < 128) ? wk + (size_t)(col - 64) * 1024
                                       : wv + (size_t)(col - 128) * 1024;
        src += step * 64 + slot * 8;
        float w[8];
        *(float4*)&w[0] = *(const float4*)(src);
        *(float4*)&w[4] = *(const float4*)(src + 4);
        bf16x8 wb;
#pragma unroll
        for (int j = 0; j < 8; ++j) wb[j] = (__bf16)w[j];
        *(bf16x8*)&Wt[(size_t)step * 12288 + col * 64 + swz8(col, slot)] = wb;
    } else {                                             // Wob chunks
        const int c2 = idx - 24576;                      // 0..8191
        const int e  = c2 >> 3;
        const int s  = c2 & 7;
        float w[8];
        *(float4*)&w[0] = *(const float4*)&wo[(size_t)e * 64 + s * 8];
        *(float4*)&w[4] = *(const float4*)&wo[(size_t)e * 64 + s * 8 + 4];
        bf16x8 wb;
#pragma unroll
        for (int j = 0; j < 8; ++j) wb[j] = (__bf16)w[j];
        *(bf16x8*)&Wob[(size_t)e * 64 + s * 8] = wb;
    }
}

// ---------------------------------------------------------------------------
// K1: QKV GEMM.  64-row tiles (512 blocks = 2/CU), 8 waves (2m x 4n), BK=64.
// W staged via global_load_lds (double-buffered, pre-swizzled source).
// x: load-early regs -> hi/lo bf16 split -> swizzled LDS.
// Q written as swizzled bf16 hi/lo; K,V as fp32.
// ---------------------------------------------------------------------------
__global__ __launch_bounds__(512) void qkv_kernel(
    const float* __restrict__ x, const __bf16* __restrict__ Wt,
    __bf16* __restrict__ Qh, __bf16* __restrict__ Ql,
    float* __restrict__ Kf, float* __restrict__ Vf)
{
    __shared__ __bf16 xh[64 * 64];
    __shared__ __bf16 xl[64 * 64];
    __shared__ __bf16 wl[2][192 * 64];

    const int tid  = threadIdx.x;
    const int lane = tid & 63;
    const int wid  = tid >> 6;
    const int lr   = lane & 15;
    const int kg   = lane >> 4;
    const int wm   = wid >> 2;          // 0..1 : 32-row group
    const int wn   = wid & 3;           // 0..3 : 48-col group
    const int row0 = blockIdx.x * 64;

    f32x4 acc[2][3];
#pragma unroll
    for (int i = 0; i < 2; ++i)
#pragma unroll
        for (int j = 0; j < 3; ++j) acc[i][j] = (f32x4){0.f, 0.f, 0.f, 0.f};

    float xv[8];

    // W tile stage: 24576 B, 3 x 1KB wave-issues per wave
#define STAGE_W(stp, buf)                                                      \
    {                                                                          \
        _Pragma("unroll")                                                      \
        for (int i = 0; i < 3; ++i) {                                          \
            const int boff = wid * 3072 + i * 1024;                            \
            gload_lds16((const char*)Wt + (size_t)(stp) * 24576 + boff + (lane << 4), \
                        (char*)&wl[buf][0] + boff);                            \
        }                                                                      \
    }
#define LOAD_X(stp)                                                            \
    {                                                                          \
        _Pragma("unroll")                                                      \
        for (int i = 0; i < 2; ++i) {                                          \
            const int s4 = tid + i * 512;                                      \
            const int r  = s4 >> 4, f4 = s4 & 15;                              \
            *(float4*)&xv[i * 4] =                                             \
                *(const float4*)&x[(size_t)(row0 + r) * 1024 + (stp) * 64 + f4 * 4]; \
        }                                                                      \
    }

    STAGE_W(0, 0);
    LOAD_X(0);

    for (int step = 0; step < 16; ++step) {
        const int cur = step & 1;
        // convert current x regs -> hi/lo, write swizzled LDS
#pragma unroll
        for (int i = 0; i < 2; ++i) {
            const int s4 = tid + i * 512;
            const int r  = s4 >> 4, f4 = s4 & 15;
            bf16x4 h, l;
#pragma unroll
            for (int j = 0; j < 4; ++j) {
                const float v = xv[i * 4 + j];
                const unsigned int bb = __float_as_uint(v);
                h[j] = __builtin_bit_cast(__bf16, (unsigned short)(bb >> 16));
                l[j] = (__bf16)(v - __uint_as_float(bb & 0xffff0000u));
            }
            const int off = r * 64 + swz8(r, f4 >> 1) + (f4 & 1) * 4;
            *(bf16x4*)&xh[off] = h;
            *(bf16x4*)&xl[off] = l;
        }
        __syncthreads();                     // x visible; wl[cur] complete
        if (step < 15) {                     // prefetch next tile under MFMA
            STAGE_W(step + 1, cur ^ 1);
            LOAD_X(step + 1);
        }
#pragma unroll
        for (int ks = 0; ks < 2; ++ks) {
            const int slot = ks * 4 + kg;
            bf16x8 Ah[2], Al[2], Bw[3];
#pragma unroll
            for (int am = 0; am < 2; ++am) {
                const int row = wm * 32 + am * 16 + lr;
                Ah[am] = *(const bf16x8*)&xh[row * 64 + swz8(row, slot)];
                Al[am] = *(const bf16x8*)&xl[row * 64 + swz8(row, slot)];
            }
#pragma unroll
            for (int bn = 0; bn < 3; ++bn) {
                const int col = wn * 48 + bn * 16 + lr;
                Bw[bn] = *(const bf16x8*)&wl[cur][col * 64 + swz8(col, slot)];
            }
#pragma unroll
            for (int am = 0; am < 2; ++am)
#pragma unroll
                for (int bn = 0; bn < 3; ++bn) {
                    acc[am][bn] = MFMA_BF16(Ah[am], Bw[bn], acc[am][bn]);
                    acc[am][bn] = MFMA_BF16(Al[am], Bw[bn], acc[am][bn]);
                }
        }
        __syncthreads();
    }
#undef STAGE_W
#undef LOAD_X

    // epilogue: C/D layout col=lane&15, row=(lane>>4)*4+reg
#pragma unroll
    for (int am = 0; am < 2; ++am)
#pragma unroll
        for (int bn = 0; bn < 3; ++bn) {
            const int col  = wn * 48 + bn * 16 + lr;
            const int rowb = row0 + wm * 32 + am * 16 + kg * 4;
            if (col < 64) {
#pragma unroll
                for (int r = 0; r < 4; ++r) {
                    const int n   = rowb + r;
                    const float v = acc[am][bn][r];
                    const __bf16 h = (__bf16)v;
                    const __bf16 l = (__bf16)(v - (float)h);
                    const size_t o = (size_t)n * 64 + swz8(n, col >> 3) + (col & 7);
                    Qh[o] = h; Ql[o] = l;
                }
            } else if (col < 128) {
#pragma unroll
                for (int r = 0; r < 4; ++r)
                    Kf[(size_t)(rowb + r) * 64 + (col - 64)] = acc[am][bn][r];
            } else {
#pragma unroll
                for (int r = 0; r < 4; ++r)
                    Vf[(size_t)(rowb + r) * 64 + (col - 128)] = acc[am][bn][r];
            }
        }
}

// ---------------------------------------------------------------------------
// K2: partial energy over 128-row blocks.  part[blk][d][e] = sum K[n,d]V[n,e]
// K/V staged by global_load_lds; broadcast-pattern LDS reads (conflict-free).
// ---------------------------------------------------------------------------
__global__ __launch_bounds__(512) void energy_partial_kernel(
    const float* __restrict__ Kf, const float* __restrict__ Vf,
    float* __restrict__ part)
{
    __shared__ float lK[32 * 64];
    __shared__ float lV[32 * 64];
    const int tid  = threadIdx.x;
    const int lane = tid & 63;
    const int wid  = tid >> 6;
    const int d    = tid >> 3;           // 0..63
    const int e0   = (tid & 7) * 8;      // 0..56
    const int row0 = blockIdx.x * 128;

    float acc[8] = {0.f, 0.f, 0.f, 0.f, 0.f, 0.f, 0.f, 0.f};

    for (int c = 0; c < 4; ++c) {
        const size_t boff = (size_t)(row0 + c * 32) * 256 + wid * 1024 + (lane << 4);
        gload_lds16((const char*)Kf + boff, (char*)lK + wid * 1024);
        gload_lds16((const char*)Vf + boff, (char*)lV + wid * 1024);
        __syncthreads();
        for (int n = 0; n < 32; ++n) {
            const float kv = lK[n * 64 + d];
            const float4 a = *(const float4*)&lV[n * 64 + e0];
            const float4 b = *(const float4*)&lV[n * 64 + e0 + 4];
            acc[0] += kv * a.x; acc[1] += kv * a.y; acc[2] += kv * a.z; acc[3] += kv * a.w;
            acc[4] += kv * b.x; acc[5] += kv * b.y; acc[6] += kv * b.z; acc[7] += kv * b.w;
        }
        __syncthreads();
    }
    float* p = part + (size_t)blockIdx.x * 4096 + d * 64 + e0;
    *(float4*)&p[0] = make_float4(acc[0], acc[1], acc[2], acc[3]);
    *(float4*)&p[4] = make_float4(acc[4], acc[5], acc[6], acc[7]);
}

// K2b: reduce partials, fold sqrt(3/64), emit E^T as swizzled bf16 hi/lo
// layout Eth[b][ e*64 + swz(d) ] so K3 B-frags are direct 16B loads.
__global__ __launch_bounds__(256) void energy_reduce_kernel(
    const float* __restrict__ part, __bf16* __restrict__ Eth, __bf16* __restrict__ Etl)
{
    const int b    = blockIdx.x >> 4;
    const int elem = ((blockIdx.x & 15) << 8) + threadIdx.x;   // d*64+e
    float s = 0.f;
#pragma unroll 8
    for (int c = 0; c < 64; ++c)
        s += part[(size_t)(b * 64 + c) * 4096 + elem];
    s *= 0.2165063509461097f;                                  // sqrt(3/64)
    const int d = elem >> 6, e = elem & 63;
    const __bf16 h = (__bf16)s;
    const __bf16 l = (__bf16)(s - (float)h);
    const size_t o = (size_t)b * 4096 + e * 64 + swz8(e, d >> 3) + (d & 7);
    Eth[o] = h; Etl[o] = l;
}

// ---------------------------------------------------------------------------
// K3: out = ctx @ wo^T, ctx = Q @ E.  64-row tiles (512 blocks), 8 waves.
// Q staged by global_load_lds (pre-swizzled layout); ctx via MFMA; ctx
// transposed hi/lo through LDS; wo B-frags read straight from L2 (bf16).
// ---------------------------------------------------------------------------
__global__ __launch_bounds__(512) void out_kernel(
    const __bf16* __restrict__ Qh, const __bf16* __restrict__ Ql,
    const __bf16* __restrict__ Eth, const __bf16* __restrict__ Etl,
    const __bf16* __restrict__ Wob, float* __restrict__ out)
{
    __shared__ __bf16 qh[64 * 64];
    __shared__ __bf16 ql[64 * 64];
    __shared__ __bf16 ch[64 * 64];
    __shared__ __bf16 cl[64 * 64];

    const int tid  = threadIdx.x;
    const int lane = tid & 63;
    const int wid  = tid >> 6;
    const int lr   = lane & 15;
    const int kg   = lane >> 4;
    const int wm   = wid >> 2;          // 0..1
    const int wn   = wid & 3;           // 0..3
    const int row0 = blockIdx.x * 64;
    const int b    = blockIdx.x >> 7;   // 128 blocks per batch

    // stage Q hi/lo (8 KB each; layout already swizzled in global)
    gload_lds16((const char*)Qh + (size_t)row0 * 128 + wid * 1024 + (lane << 4),
                (char*)qh + wid * 1024);
    gload_lds16((const char*)Ql + (size_t)row0 * 128 + wid * 1024 + (lane << 4),
                (char*)ql + wid * 1024);
    __syncthreads();

    // ---- ctx = Q @ E via MFMA; each wave: 32 rows x 16 e-cols ----
    f32x4 cacc[2];
    cacc[0] = (f32x4){0.f, 0.f, 0.f, 0.f};
    cacc[1] = (f32x4){0.f, 0.f, 0.f, 0.f};
#pragma unroll
    for (int ks = 0; ks < 2; ++ks) {
        const int slot = ks * 4 + kg;
        const int e    = wn * 16 + lr;
        const bf16x8 Bh = *(const bf16x8*)&Eth[(size_t)b * 4096 + e * 64 + swz8(e, slot)];
        const bf16x8 Bl = *(const bf16x8*)&Etl[(size_t)b * 4096 + e * 64 + swz8(e, slot)];
#pragma unroll
        for (int am = 0; am < 2; ++am) {
            const int row = wm * 32 + am * 16 + lr;
            const bf16x8 Ah = *(const bf16x8*)&qh[row * 64 + swz8(row, slot)];
            const bf16x8 Al = *(const bf16x8*)&ql[row * 64 + swz8(row, slot)];
            cacc[am] = MFMA_BF16(Ah, Bh, cacc[am]);
            cacc[am] = MFMA_BF16(Ah, Bl, cacc[am]);
            cacc[am] = MFMA_BF16(Al, Bh, cacc[am]);
        }
    }
    // write ctx (transposed via C-layout) hi/lo into swizzled LDS
#pragma unroll
    for (int am = 0; am < 2; ++am)
#pragma unroll
        for (int r = 0; r < 4; ++r) {
            const int n = wm * 32 + am * 16 + kg * 4 + r;
            const int dd = wn * 16 + lr;
            const float v  = cacc[am][r];
            const __bf16 h = (__bf16)v;
            const __bf16 l = (__bf16)(v - (float)h);
            const int off = n * 64 + swz8(n, dd >> 3) + (dd & 7);
            ch[off] = h; cl[off] = l;
        }
    __syncthreads();

    // ---- out GEMM: each wave 32 rows x 256 cols; A held in regs ----
    bf16x8 Ah[2][2], Al[2][2];
#pragma unroll
    for (int am = 0; am < 2; ++am)
#pragma unroll
        for (int ks = 0; ks < 2; ++ks) {
            const int row  = wm * 32 + am * 16 + lr;
            const int slot = ks * 4 + kg;
            Ah[am][ks] = *(const bf16x8*)&ch[row * 64 + swz8(row, slot)];
            Al[am][ks] = *(const bf16x8*)&cl[row * 64 + swz8(row, slot)];
        }
#pragma unroll
    for (int g = 0; g < 4; ++g) {
        f32x4 oacc[2][4];
#pragma unroll
        for (int i = 0; i < 2; ++i)
#pragma unroll
            for (int j = 0; j < 4; ++j) oacc[i][j] = (f32x4){0.f, 0.f, 0.f, 0.f};
#pragma unroll
        for (int ks = 0; ks < 2; ++ks) {
            bf16x8 Bw[4];
#pragma unroll
            for (int bn = 0; bn < 4; ++bn) {
                const int col = wn * 256 + g * 64 + bn * 16 + lr;
                Bw[bn] = *(const bf16x8*)&Wob[(size_t)col * 64 + ks * 32 + kg * 8];
            }
#pragma unroll
            for (int am = 0; am < 2; ++am)
#pragma unroll
                for (int bn = 0; bn < 4; ++bn) {
                    oacc[am][bn] = MFMA_BF16(Ah[am][ks], Bw[bn], oacc[am][bn]);
                    oacc[am][bn] = MFMA_BF16(Al[am][ks], Bw[bn], oacc[am][bn]);
                }
        }
#pragma unroll
        for (int am = 0; am < 2; ++am)
#pragma unroll
            for (int bn = 0; bn < 4; ++bn) {
                const int gcol = wn * 256 + g * 64 + bn * 16 + lr;
                const int grow = row0 + wm * 32 + am * 16 + kg * 4;
#pragma unroll
                for (int r = 0; r < 4; ++r)
                    __builtin_nontemporal_store(oacc[am][bn][r],
                        &out[(size_t)(grow + r) * 1024 + gcol]);
            }
    }
}

extern "C" void kernel_launch(void* const* d_in, const int* in_sizes, int n_in,
                              void* d_out, int out_size, void* d_ws, size_t ws_size,
                              hipStream_t stream)
{
    const float* x  = (const float*)d_in[0];
    const float* wq = (const float*)d_in[1];
    const float* wk = (const float*)d_in[2];
    const float* wv = (const float*)d_in[3];
    const float* wo = (const float*)d_in[4];
    float* out = (float*)d_out;

    char* ws = (char*)d_ws;
    __bf16* Qh   = (__bf16*)(ws);                         // 4 MB
    __bf16* Ql   = (__bf16*)(ws + 4194304);               // 4 MB
    float*  Kf   = (float*)(ws + 8388608);                // 8 MB
    float*  Vf   = (float*)(ws + 16777216);               // 8 MB
    float*  part = (float*)(ws + 25165824);               // 4 MB (256*4096*4)
    __bf16* Wt   = (__bf16*)(ws + 25165824);              // 384 KB (overlaps part:
                                                          //  Wt dead after K1, part born in K2)
    __bf16* Eth  = (__bf16*)(ws + 29360128);              // 32 KB
    __bf16* Etl  = (__bf16*)(ws + 29392896);              // 32 KB
    __bf16* Wob  = (__bf16*)(ws + 29425664);              // 128 KB

    prep_kernel<<<128, 256, 0, stream>>>(wq, wk, wv, wo, Wt, Wob);
    qkv_kernel<<<512, 512, 0, stream>>>(x, Wt, Qh, Ql, Kf, Vf);
    energy_partial_kernel<<<256, 512, 0, stream>>>(Kf, Vf, part);
    energy_reduce_kernel<<<64, 256, 0, stream>>>(part, Eth, Etl);
    out_kernel<<<512, 512, 0, stream>>>(Qh, Ql, Eth, Etl, Wob, out);
}